// Round 6
// baseline (38.213 us; speedup 1.0000x reference)
//
#include <hip/hip_runtime.h>

#define P 1024
#define NB 11
#define NBINS 1331          // 11^3
#define BATCH 8
#define TI 8                // i-rows per block
#define NIT (P / TI)        // 128 i-tiles per batch
#define NBLKB (NIT * 2)     // 256 main blocks per batch (2 j-halves)

// force a (block-uniform) float into an SGPR
#define RFL(f) __uint_as_float(__builtin_amdgcn_readfirstlane(__float_as_uint(f)))

// Directed-pair kernel. Each block: 8-row i-tile (SGPR-resident) x 512 j
// (half the point set; 2 register-prefetched tiles of 256). Grid 2048 blocks
// = exactly 8 blocks/CU x 256 CU at VGPR<=64 -> 100% occupancy.
__global__ __launch_bounds__(256, 8) void fpfh_main(const float* __restrict__ x,
                                                    int* __restrict__ part,
                                                    int npart) {
    __shared__ int shist[NBINS];

    const int t     = threadIdx.x;
    const int b     = blockIdx.y;
    const int itile = blockIdx.x >> 1;
    const int jhalf = blockIdx.x & 1;
    const int i0    = itile * TI;
    const float* xb = x + b * (P * 6);

    for (int z = t; z < NBINS; z += 256) shist[z] = 0;

    // ---- 8 i-points into SGPRs (block-uniform) ----
    float PIX[TI], PIY[TI], PIZ[TI], NIX[TI], NIY[TI], NIZ[TI], NII[TI], SNI[TI];
    #pragma unroll
    for (int il = 0; il < TI; ++il) {
        const float* xi = xb + (i0 + il) * 6;
        PIX[il] = RFL(xi[0]); PIY[il] = RFL(xi[1]); PIZ[il] = RFL(xi[2]);
        NIX[il] = RFL(xi[3]); NIY[il] = RFL(xi[4]); NIZ[il] = RFL(xi[5]);
        float nii = fmaf(NIX[il], NIX[il], fmaf(NIY[il], NIY[il], NIZ[il] * NIZ[il]));
        NII[il] = RFL(nii);                              // |ni|^2
        SNI[il] = RFL(__builtin_amdgcn_sqrtf(nii));      // |ni|
    }

    // ---- prefetch this thread's 2 j-points (coalesced, L1/L2-resident) ----
    float pjx[2], pjy[2], pjz[2], njx[2], njy[2], njz[2];
    #pragma unroll
    for (int jt = 0; jt < 2; ++jt) {
        const float* xj = xb + (jhalf * 512 + jt * 256 + t) * 6;
        pjx[jt] = xj[0]; pjy[jt] = xj[1]; pjz[jt] = xj[2];
        njx[jt] = xj[3]; njy[jt] = xj[4]; njz[jt] = xj[5];
    }

    __syncthreads();   // shist zeroed

    #pragma unroll
    for (int jt = 0; jt < 2; ++jt) {
        const int j = jhalf * 512 + jt * 256 + t;

        #pragma unroll
        for (int il = 0; il < TI; ++il) {
            // delta = pos_j - pos_i
            const float dx = pjx[jt] - PIX[il];
            const float dy = pjy[jt] - PIY[il];
            const float dz = pjz[jt] - PIZ[il];

            const float dd    = fmaf(dx, dx, fmaf(dy, dy, dz * dz));
            const float nid   = fmaf(NIX[il], dx, fmaf(NIY[il], dy, NIZ[il] * dz));
            const float nidnj = fmaf(NIX[il], njx[jt],
                                fmaf(NIY[il], njy[jt], NIZ[il] * njz[jt]));
            const float ddnj  = fmaf(dx, njx[jt], fmaf(dy, njy[jt], dz * njz[jt]));

            // cv = delta x ni ;  cv . nj
            const float cvx = fmaf(dy, NIZ[il], -(dz * NIY[il]));
            const float cvy = fmaf(dz, NIX[il], -(dx * NIZ[il]));
            const float cvz = fmaf(dx, NIY[il], -(dy * NIX[il]));
            const float cvdnj = fmaf(cvx, njx[jt],
                                fmaf(cvy, njy[jt], cvz * njz[jt]));

            // |cv|^2 = dd*|ni|^2 - (ni.d)^2   (Lagrange; cv ⟂ ni)
            float cvv = fmaxf(fmaf(dd, NII[il], -(nid * nid)), 0.0f);
            const float rs    = __builtin_amdgcn_rsqf(cvv);
            const float alpha = cvdnj * rs;
            const float scv   = cvv * rs;                 // |cv|

            const float phi = nid * __builtin_amdgcn_rsqf(dd);

            // theta = atan2(y, x): y = cw.nj = |ni|^2(d.nj) - (ni.d)(ni.nj),
            //                      x = |ni||cv| * (ni.nj)
            // binned via cot|theta| against cot((2m-1)pi/11), m=1..5
            const float y_t = fmaf(NII[il], ddnj, -(nid * nidnj));
            const float x_t = (SNI[il] * nidnj) * scv;
            const float tq  = x_t * __builtin_amdgcn_rcpf(__builtin_fabsf(y_t));
            int kk = (tq <  3.40568625f) + (tq <  0.86650494f) + (tq < 0.14377830f)
                   + (tq < -0.45668469f) + (tq < -1.55603037f);
            const int ith = (y_t < 0.0f) ? 5 - kk : 5 + kk;   // in [0,10]

            int ia = min((int)fmaf(alpha, 5.5f, 5.5f), NB - 1);
            int ip = min((int)fmaf(phi,   5.5f, 5.5f), NB - 1);

            int bin = (ia * NB + ip) * NB + ith;
            if (bin < 0) bin += NBINS;               // JAX wrap-once
            if ((j != i0 + il) && ((unsigned)bin < (unsigned)NBINS))
                atomicAdd(&shist[bin], 1);           // still-OOB dropped
        }
    }
    __syncthreads();

    if (npart == NBLKB) {
        // exclusive slot per block: plain stores, no zeroing needed
        int* slot = part + (b * NBLKB + blockIdx.x) * NBINS;
        for (int z = t; z < NBINS; z += 256) slot[z] = shist[z];
    } else {
        // shared slots (pre-zeroed by host memset): int atomics, deterministic
        int* slot = part + (b * npart + (blockIdx.x % npart)) * NBINS;
        for (int z = t; z < NBINS; z += 256) {
            int c = shist[z];
            if (c) atomicAdd(&slot[z], c);
        }
    }
}

// 4 threads per (batch, bin); each sums partials k = q, q+4, ... (fixed-order
// int adds -> deterministic), then two shfl_xor combines; q==0 lane stores.
__global__ __launch_bounds__(256) void fpfh_reduce(const int* __restrict__ part,
                                                   float* __restrict__ out,
                                                   int npart) {
    const int tid = blockIdx.x * 256 + threadIdx.x;
    const int o   = tid >> 2;            // output index = b*NBINS + bin
    const int q   = tid & 3;
    int s = 0;
    if (o < BATCH * NBINS) {
        const int b   = o / NBINS;
        const int bin = o - b * NBINS;
        const int* p  = part + (size_t)b * npart * NBINS + bin;
        for (int k = q; k < npart; k += 4)
            s += p[(size_t)k * NBINS];
    }
    s += __shfl_xor(s, 1);
    s += __shfl_xor(s, 2);
    if (q == 0 && o < BATCH * NBINS)
        out[o] = (float)s * (1.0f / 1047552.0f);   // / (P*(P-1))
}

extern "C" void kernel_launch(void* const* d_in, const int* in_sizes, int n_in,
                              void* d_out, int out_size, void* d_ws, size_t ws_size,
                              hipStream_t stream) {
    const float* x = (const float*)d_in[0];
    float* out = (float*)d_out;
    int* part  = (int*)d_ws;

    const size_t slot_bytes = (size_t)BATCH * NBINS * sizeof(int);    // 42,592 B
    const size_t need_excl  = slot_bytes * NBLKB;                     // ~10.9 MB
    int npart;
    if (ws_size >= need_excl) {
        npart = NBLKB;                // exclusive slots: no zeroing, no atomics
    } else {
        npart = (int)(ws_size / slot_bytes);
        if (npart < 1)     npart = 1;
        if (npart > NIT)   npart = NIT;
        hipMemsetAsync(d_ws, 0, slot_bytes * npart, stream);   // graph-legal
    }

    dim3 grid(NBLKB, BATCH);          // 256 x-blocks x 8 batches = 2048 blocks
    fpfh_main<<<grid, 256, 0, stream>>>(x, part, npart);

    const int nThreads = BATCH * NBINS * 4;
    fpfh_reduce<<<(nThreads + 255) / 256, 256, 0, stream>>>(part, out, npart);
}

// Round 7
// 30.284 us; speedup vs baseline: 1.2619x; 1.2619x over previous
//
#include <hip/hip_runtime.h>

#define P 1024
#define NB 11
#define NBINS 1331          // 11^3
#define BATCH 8
#define TI 8                // i-rows per block
#define NIT (P / TI)        // 128 i-tiles (= main blocks) per batch
#define BLKT 512            // threads per main block

// force a (block-uniform) float into an SGPR
#define RFL(f) __uint_as_float(__builtin_amdgcn_readfirstlane(__float_as_uint(f)))

// Directed-pair kernel, R5 structure with 512-thread blocks for 100% occupancy:
// 1024 blocks = 4 blocks/CU x 8 waves = 32 waves/CU (R5 was 16). Each block:
// 8-row i-tile (SGPR-resident) x all 1024 j (2 register-prefetched j-points
// per thread). Flush: exclusive slot per block (plain stores, no zeroing) when
// ws allows; else atomic into shared slots pre-zeroed by memset.
__global__ __launch_bounds__(BLKT, 8) void fpfh_main(const float* __restrict__ x,
                                                     int* __restrict__ part,
                                                     int npart) {
    __shared__ int shist[NBINS];

    const int t  = threadIdx.x;
    const int b  = blockIdx.y;
    const int i0 = blockIdx.x * TI;
    const float* xb = x + b * (P * 6);

    for (int z = t; z < NBINS; z += BLKT) shist[z] = 0;

    // ---- 8 i-points into SGPRs (block-uniform) ----
    float PIX[TI], PIY[TI], PIZ[TI], NIX[TI], NIY[TI], NIZ[TI], NII[TI], SNI[TI];
    #pragma unroll
    for (int il = 0; il < TI; ++il) {
        const float* xi = xb + (i0 + il) * 6;
        PIX[il] = RFL(xi[0]); PIY[il] = RFL(xi[1]); PIZ[il] = RFL(xi[2]);
        NIX[il] = RFL(xi[3]); NIY[il] = RFL(xi[4]); NIZ[il] = RFL(xi[5]);
        float nii = fmaf(NIX[il], NIX[il], fmaf(NIY[il], NIY[il], NIZ[il] * NIZ[il]));
        NII[il] = RFL(nii);                              // |ni|^2
        SNI[il] = RFL(__builtin_amdgcn_sqrtf(nii));      // |ni|
    }

    // ---- prefetch this thread's 2 j-points (coalesced, L1/L2-resident) ----
    float pjx[2], pjy[2], pjz[2], njx[2], njy[2], njz[2];
    #pragma unroll
    for (int jt = 0; jt < 2; ++jt) {
        const float* xj = xb + (jt * BLKT + t) * 6;
        pjx[jt] = xj[0]; pjy[jt] = xj[1]; pjz[jt] = xj[2];
        njx[jt] = xj[3]; njy[jt] = xj[4]; njz[jt] = xj[5];
    }

    __syncthreads();   // shist zeroed

    #pragma unroll
    for (int jt = 0; jt < 2; ++jt) {
        const int j = jt * BLKT + t;

        #pragma unroll
        for (int il = 0; il < TI; ++il) {
            // delta = pos_j - pos_i
            const float dx = pjx[jt] - PIX[il];
            const float dy = pjy[jt] - PIY[il];
            const float dz = pjz[jt] - PIZ[il];

            const float dd    = fmaf(dx, dx, fmaf(dy, dy, dz * dz));
            const float nid   = fmaf(NIX[il], dx, fmaf(NIY[il], dy, NIZ[il] * dz));
            const float nidnj = fmaf(NIX[il], njx[jt],
                                fmaf(NIY[il], njy[jt], NIZ[il] * njz[jt]));
            const float ddnj  = fmaf(dx, njx[jt], fmaf(dy, njy[jt], dz * njz[jt]));

            // cv = delta x ni ;  cv . nj
            const float cvx = fmaf(dy, NIZ[il], -(dz * NIY[il]));
            const float cvy = fmaf(dz, NIX[il], -(dx * NIZ[il]));
            const float cvz = fmaf(dx, NIY[il], -(dy * NIX[il]));
            const float cvdnj = fmaf(cvx, njx[jt],
                                fmaf(cvy, njy[jt], cvz * njz[jt]));

            // |cv|^2 = dd*|ni|^2 - (ni.d)^2   (Lagrange; cv ⟂ ni)
            float cvv = fmaxf(fmaf(dd, NII[il], -(nid * nid)), 0.0f);
            const float rs    = __builtin_amdgcn_rsqf(cvv);
            const float alpha = cvdnj * rs;
            const float scv   = cvv * rs;                 // |cv|

            const float phi = nid * __builtin_amdgcn_rsqf(dd);

            // theta = atan2(y, x): y = cw.nj = |ni|^2(d.nj) - (ni.d)(ni.nj),
            //                      x = |ni||cv| * (ni.nj)
            // binned via cot|theta| against cot((2m-1)pi/11), m=1..5
            const float y_t = fmaf(NII[il], ddnj, -(nid * nidnj));
            const float x_t = (SNI[il] * nidnj) * scv;
            const float tq  = x_t * __builtin_amdgcn_rcpf(__builtin_fabsf(y_t));
            int kk = (tq <  3.40568625f) + (tq <  0.86650494f) + (tq < 0.14377830f)
                   + (tq < -0.45668469f) + (tq < -1.55603037f);
            const int ith = (y_t < 0.0f) ? 5 - kk : 5 + kk;   // in [0,10]

            int ia = min((int)fmaf(alpha, 5.5f, 5.5f), NB - 1);
            int ip = min((int)fmaf(phi,   5.5f, 5.5f), NB - 1);

            int bin = (ia * NB + ip) * NB + ith;
            if (bin < 0) bin += NBINS;               // JAX wrap-once
            if ((j != i0 + il) && ((unsigned)bin < (unsigned)NBINS))
                atomicAdd(&shist[bin], 1);           // still-OOB dropped
        }
    }
    __syncthreads();

    if (npart == NIT) {
        // exclusive slot per block: plain stores, no zeroing needed
        int* slot = part + (b * NIT + blockIdx.x) * NBINS;
        for (int z = t; z < NBINS; z += BLKT) slot[z] = shist[z];
    } else {
        // shared slots (pre-zeroed by host memset): int atomics, deterministic
        int* slot = part + (b * npart + (blockIdx.x % npart)) * NBINS;
        for (int z = t; z < NBINS; z += BLKT) {
            int c = shist[z];
            if (c) atomicAdd(&slot[z], c);
        }
    }
}

// 4 threads per (batch, bin); each sums partials k = q, q+4, ... (fixed-order
// int adds -> deterministic), then two shfl_xor combines; q==0 lane stores.
__global__ __launch_bounds__(256) void fpfh_reduce(const int* __restrict__ part,
                                                   float* __restrict__ out,
                                                   int npart) {
    const int tid = blockIdx.x * 256 + threadIdx.x;
    const int o   = tid >> 2;            // output index = b*NBINS + bin
    const int q   = tid & 3;
    int s = 0;
    if (o < BATCH * NBINS) {
        const int b   = o / NBINS;
        const int bin = o - b * NBINS;
        const int* p  = part + (size_t)b * npart * NBINS + bin;
        for (int k = q; k < npart; k += 4)
            s += p[(size_t)k * NBINS];
    }
    s += __shfl_xor(s, 1);
    s += __shfl_xor(s, 2);
    if (q == 0 && o < BATCH * NBINS)
        out[o] = (float)s * (1.0f / 1047552.0f);   // / (P*(P-1))
}

extern "C" void kernel_launch(void* const* d_in, const int* in_sizes, int n_in,
                              void* d_out, int out_size, void* d_ws, size_t ws_size,
                              hipStream_t stream) {
    const float* x = (const float*)d_in[0];
    float* out = (float*)d_out;
    int* part  = (int*)d_ws;

    const size_t slot_bytes = (size_t)BATCH * NBINS * sizeof(int);   // 42,592 B
    const size_t need_excl  = slot_bytes * NIT;                      // ~5.45 MB
    int npart;
    if (ws_size >= need_excl) {
        npart = NIT;                  // exclusive slots: no zeroing, no atomics
    } else {
        npart = (int)(ws_size / slot_bytes);
        if (npart < 1)   npart = 1;
        if (npart > NIT) npart = NIT;
        hipMemsetAsync(d_ws, 0, slot_bytes * npart, stream);   // graph-legal
    }

    dim3 grid(NIT, BATCH);            // 128 x 8 = 1024 blocks of 512 threads
    fpfh_main<<<grid, BLKT, 0, stream>>>(x, part, npart);

    const int nThreads = BATCH * NBINS * 4;
    fpfh_reduce<<<(nThreads + 255) / 256, 256, 0, stream>>>(part, out, npart);
}